// Round 1
// baseline (120.605 us; speedup 1.0000x reference)
//
#include <hip/hip_runtime.h>
#include <hip/hip_bf16.h>
#include <math.h>

#define N_SPANS 4096
#define EMB 384
#define HEADS 4
#define HE (HEADS * EMB)   // 1536
#define BAND 11            // exp(-12/5)=0.0907 < 0.1 => |i-j|>=12 can never pass threshold
#define BW (2 * BAND + 1)  // 23

typedef short bf16x8 __attribute__((ext_vector_type(8)));
typedef float f32x4 __attribute__((ext_vector_type(4)));
typedef unsigned short u16x8 __attribute__((ext_vector_type(8)));

__device__ __forceinline__ unsigned short f2bf(float f) {
    union { float f; unsigned u; } x; x.f = f;
    unsigned r = x.u + 0x7fffu + ((x.u >> 16) & 1u);  // RNE
    return (unsigned short)(r >> 16);
}

__device__ __forceinline__ float wave_sum(float v) {
    #pragma unroll
    for (int off = 32; off; off >>= 1) v += __shfl_xor(v, off, 64);
    return v;
}
__device__ __forceinline__ float wave_max(float v) {
    #pragma unroll
    for (int off = 32; off; off >>= 1) v = fmaxf(v, __shfl_xor(v, off, 64));
    return v;
}

// ---------------------------------------------------------------- row norms
__global__ __launch_bounds__(256) void row_norms(const float* __restrict__ E,
                                                 float* __restrict__ invn) {
    int n = blockIdx.x * 4 + (threadIdx.x >> 6);
    int lane = threadIdx.x & 63;
    const float* er = E + n * EMB;
    float s = 0.f;
    #pragma unroll
    for (int m = 0; m < 6; ++m) { float v = er[m * 64 + lane]; s += v * v; }
    s = wave_sum(s);
    if (lane == 0) invn[n] = 1.0f / sqrtf(s);
}

// ------------------------------------------- W [384,1536] -> Wt bf16 [1536,384]
__global__ __launch_bounds__(256) void transpose_w(const float* __restrict__ W,
                                                   unsigned short* __restrict__ Wt) {
    __shared__ float t[32][33];
    int n0 = blockIdx.x * 32;  // over 1536
    int k0 = blockIdx.y * 32;  // over 384
    int tx = threadIdx.x & 31, ty = threadIdx.x >> 5;  // ty 0..7
    #pragma unroll
    for (int q = 0; q < 4; ++q)
        t[ty + q * 8][tx] = W[(k0 + ty + q * 8) * HE + n0 + tx];
    __syncthreads();
    #pragma unroll
    for (int q = 0; q < 4; ++q)
        Wt[(n0 + ty + q * 8) * EMB + k0 + tx] = f2bf(t[tx][ty + q * 8]);
}

// ------------------------------------------------- x = E @ W  (bf16 MFMA)
// A: E fp32 [4096,384] (cast on the fly), B: Wt bf16 [1536,384] (pre-transposed)
// C: X fp32 [4096,1536]. 128x128 tile, BK=32, 4 waves each 64x64 (4x4 of 16x16x32).
__global__ __launch_bounds__(256) void gemm_proj(const float* __restrict__ E,
                                                 const unsigned short* __restrict__ Wt,
                                                 float* __restrict__ X) {
    __shared__ unsigned short As[128 * 32];
    __shared__ unsigned short Bs[128 * 32];
    const int tid = threadIdx.x;
    const int lane = tid & 63;
    const int wave = tid >> 6;
    const int m0 = blockIdx.y * 128;
    const int n0 = blockIdx.x * 128;
    const int wr = (wave >> 1) * 64;
    const int wc = (wave & 1) * 64;
    const int quad = lane >> 4;
    const int l16 = lane & 15;

    f32x4 acc[4][4];
    #pragma unroll
    for (int i = 0; i < 4; ++i)
        #pragma unroll
        for (int j = 0; j < 4; ++j) acc[i][j] = 0.f;

    for (int kt = 0; kt < 12; ++kt) {
        __syncthreads();
        // stage A: 128x32 fp32->bf16; 1024 float4 chunks, 4 per thread
        #pragma unroll
        for (int c = 0; c < 4; ++c) {
            int ch = tid + c * 256;
            int row = ch >> 3, cc = ch & 7;
            const float4 v = *(const float4*)(E + (m0 + row) * EMB + kt * 32 + cc * 4);
            ushort4 b;
            b.x = f2bf(v.x); b.y = f2bf(v.y); b.z = f2bf(v.z); b.w = f2bf(v.w);
            *(ushort4*)(&As[row * 32 + cc * 4]) = b;
        }
        // stage B: Bs[n][k] = Wt[(n0+n)*384 + kt*32 + k]; 512 u16x8 chunks, 2 per thread
        #pragma unroll
        for (int c = 0; c < 2; ++c) {
            int ch = tid + c * 256;
            int row = ch >> 2, cc = ch & 3;
            *(u16x8*)(&Bs[row * 32 + cc * 8]) =
                *(const u16x8*)(Wt + (n0 + row) * EMB + kt * 32 + cc * 8);
        }
        __syncthreads();

        bf16x8 af[4], bfr[4];
        #pragma unroll
        for (int t = 0; t < 4; ++t) {
            af[t]  = *(const bf16x8*)(&As[(wr + t * 16 + l16) * 32 + quad * 8]);
            bfr[t] = *(const bf16x8*)(&Bs[(wc + t * 16 + l16) * 32 + quad * 8]);
        }
        #pragma unroll
        for (int ti = 0; ti < 4; ++ti)
            #pragma unroll
            for (int tj = 0; tj < 4; ++tj)
                acc[ti][tj] = __builtin_amdgcn_mfma_f32_16x16x32_bf16(
                    af[ti], bfr[tj], acc[ti][tj], 0, 0, 0);
    }
    // epilogue: D row = quad*4+reg, col = l16
    #pragma unroll
    for (int ti = 0; ti < 4; ++ti)
        #pragma unroll
        for (int tj = 0; tj < 4; ++tj) {
            int col = n0 + wc + tj * 16 + l16;
            #pragma unroll
            for (int r = 0; r < 4; ++r) {
                int row = m0 + wr + ti * 16 + quad * 4 + r;
                X[row * HE + col] = acc[ti][tj][r];
            }
        }
}

// ------------------------------------- a_src/a_dst [N,H]: wave per (node,head)
__global__ __launch_bounds__(256) void att_vecs(const float* __restrict__ X,
                                                const float* __restrict__ att_src,
                                                const float* __restrict__ att_dst,
                                                float* __restrict__ asrc,
                                                float* __restrict__ adst) {
    int n = blockIdx.x;
    int lane = threadIdx.x & 63, h = threadIdx.x >> 6;
    const float* xr = X + n * HE + h * EMB;
    float ss = 0.f, sd = 0.f;
    #pragma unroll
    for (int m = 0; m < 6; ++m) {
        int e = m * 64 + lane;
        float v = xr[e];
        ss += v * att_src[h * EMB + e];
        sd += v * att_dst[h * EMB + e];
    }
    ss = wave_sum(ss);
    sd = wave_sum(sd);
    if (lane == 0) { asrc[n * HEADS + h] = ss; adst[n * HEADS + h] = sd; }
}

// ------------------------- banded mask + per-head softmax + aggregation
__global__ __launch_bounds__(256) void band_attn(const float* __restrict__ E,
                                                 const float* __restrict__ invn,
                                                 const float* __restrict__ asrc,
                                                 const float* __restrict__ adst,
                                                 const float* __restrict__ X,
                                                 const float* __restrict__ bias,
                                                 float* __restrict__ out) {
    const int i = blockIdx.x;
    const int tid = threadIdx.x;
    const int lane = tid & 63, wave = tid >> 6;

    __shared__ float ei[EMB];
    __shared__ float alpha_s[HEADS][BW];
    __shared__ int maskv[BW];
    __shared__ int list[BW];
    __shared__ int cnt;

    for (int d = tid; d < EMB; d += 256) ei[d] = E[i * EMB + d];
    __syncthreads();

    const float inv_i = invn[i];
    // fp32 banded cos-sim + decay threshold (must be fp32: threshold flips matter)
    for (int it = 0; it < 6; ++it) {
        int jo = it * 4 + wave;           // wave-uniform
        if (jo < BW) {
            int j = i - BAND + jo;
            bool valid = (j >= 0) && (j < N_SPANS);
            float s = 0.f;
            if (valid) {
                const float* ej = E + j * EMB;
                #pragma unroll
                for (int m = 0; m < 6; ++m) {
                    int d = m * 64 + lane;
                    s += ei[d] * ej[d];
                }
                s = wave_sum(s);
            }
            if (lane == 0) {
                int mflag = 0;
                if (valid) {
                    float cosv = s * inv_i * invn[j];
                    int dd = jo - BAND; if (dd < 0) dd = -dd;
                    float a = cosv * expf(-(float)dd * 0.2f);
                    if (a > 0.1f) mflag = 1;
                }
                maskv[jo] = mflag;
            }
        }
    }
    __syncthreads();

    // per-head masked softmax over the 23-wide band: wave w = head w
    {
        const int h = wave;
        const int jo = lane;
        float logit = -INFINITY;
        if (jo < BW && maskv[jo]) {
            int j = i - BAND + jo;
            float z = adst[i * HEADS + h] + asrc[j * HEADS + h];
            logit = (z >= 0.f) ? z : 0.2f * z;   // leaky_relu 0.2
        }
        float mx = wave_max(logit);              // diag always present -> finite
        float ex = (jo < BW) ? expf(logit - mx) : 0.f;
        float sm = wave_sum(ex);
        if (jo < BW) alpha_s[h][jo] = ex / sm;
    }
    __syncthreads();

    if (tid == 0) {
        int c = 0;
        for (int jo = 0; jo < BW; ++jo) if (maskv[jo]) list[c++] = jo;
        cnt = c;
    }
    __syncthreads();

    const int c = cnt;
    for (int e = tid; e < EMB; e += 256) {
        float acc = 0.f;
        for (int ii = 0; ii < c; ++ii) {
            int jo = list[ii];
            int j = i - BAND + jo;
            const float* xb = X + j * HE + e;
            #pragma unroll
            for (int h = 0; h < HEADS; ++h)
                acc += alpha_s[h][jo] * xb[h * EMB];
        }
        out[i * EMB + e] = 0.25f * acc + bias[e];  // mean over 4 heads + bias
    }
}

extern "C" void kernel_launch(void* const* d_in, const int* in_sizes, int n_in,
                              void* d_out, int out_size, void* d_ws, size_t ws_size,
                              hipStream_t stream) {
    const float* E       = (const float*)d_in[0];
    // d_in[1] span_positions: unused by the reference computation
    const float* W       = (const float*)d_in[2];
    const float* att_src = (const float*)d_in[3];
    const float* att_dst = (const float*)d_in[4];
    const float* bias    = (const float*)d_in[5];
    float* out = (float*)d_out;

    char* ws = (char*)d_ws;
    float* X            = (float*)ws;                              // 4096*1536*4 = 25165824 B
    unsigned short* Wt  = (unsigned short*)(ws + 25165824);        // 1536*384*2  = 1179648 B
    float* invn         = (float*)(ws + 25165824 + 1179648);       // 4096*4
    float* asrc         = invn + 4096;                             // 4096*4*4
    float* adst         = asrc + 4096 * HEADS;                     // 4096*4*4

    row_norms<<<1024, 256, 0, stream>>>(E, invn);
    transpose_w<<<dim3(48, 12), 256, 0, stream>>>(W, Wt);
    gemm_proj<<<dim3(12, 32), 256, 0, stream>>>(E, Wt, X);
    att_vecs<<<4096, 256, 0, stream>>>(X, att_src, att_dst, asrc, adst);
    band_attn<<<4096, 256, 0, stream>>>(E, invn, asrc, adst, X, bias, out);
}

// Round 2
// 119.155 us; speedup vs baseline: 1.0122x; 1.0122x over previous
//
#include <hip/hip_runtime.h>
#include <hip/hip_bf16.h>
#include <math.h>

#define N_SPANS 4096
#define EMB 384
#define HEADS 4
#define HE (HEADS * EMB)   // 1536
#define BAND 11            // exp(-12/5)=0.0907 < 0.1 => |i-j|>=12 never passes threshold
#define BW (2 * BAND + 1)  // 23

typedef short bf16x8 __attribute__((ext_vector_type(8)));
typedef float f32x4 __attribute__((ext_vector_type(4)));

__device__ __forceinline__ unsigned short f2bf(float f) {
    union { float f; unsigned u; } x; x.f = f;
    unsigned r = x.u + 0x7fffu + ((x.u >> 16) & 1u);  // RNE
    return (unsigned short)(r >> 16);
}
__device__ __forceinline__ float bf2f(unsigned short u) {
    union { unsigned u; float f; } x; x.u = ((unsigned)u) << 16; return x.f;
}

__device__ __forceinline__ float wave_sum(float v) {
    #pragma unroll
    for (int off = 32; off; off >>= 1) v += __shfl_xor(v, off, 64);
    return v;
}
__device__ __forceinline__ float wave_max(float v) {
    #pragma unroll
    for (int off = 32; off; off >>= 1) v = fmaxf(v, __shfl_xor(v, off, 64));
    return v;
}

// async global->LDS, 16B per lane, dest = wave-uniform base + lane*16
__device__ __forceinline__ void gl2lds16(const void* g, void* l) {
    __builtin_amdgcn_global_load_lds(
        (const __attribute__((address_space(1))) void*)(uintptr_t)g,
        (__attribute__((address_space(3))) void*)(unsigned)(uintptr_t)l,
        16, 0, 0);
}

// ------------------------------------------------------------------ prep
// blocks [0,1024): row inv-norms + E fp32->bf16 cast (wave per row)
// blocks [1024,1600): W [384,1536] -> Wt bf16 [1536,384]
// blocks [1600,1632): zero asrc/adst (32768 floats)
__global__ __launch_bounds__(256) void prep(const float* __restrict__ E,
                                            const float* __restrict__ W,
                                            unsigned short* __restrict__ Ebf,
                                            unsigned short* __restrict__ Wt,
                                            float* __restrict__ invn,
                                            float* __restrict__ attacc) {
    __shared__ float tile[32][33];
    const int b = blockIdx.x;
    const int tid = threadIdx.x;
    if (b < 1024) {
        const int lane = tid & 63, w = tid >> 6;
        const int n = b * 4 + w;
        const float4* er = (const float4*)(E + n * EMB);  // 96 chunks
        unsigned short* orow = Ebf + n * EMB;
        float s = 0.f;
        float4 v0 = er[lane];
        s += v0.x * v0.x + v0.y * v0.y + v0.z * v0.z + v0.w * v0.w;
        ushort4 c0;
        c0.x = f2bf(v0.x); c0.y = f2bf(v0.y); c0.z = f2bf(v0.z); c0.w = f2bf(v0.w);
        ((ushort4*)orow)[lane] = c0;
        if (lane < 32) {
            float4 v1 = er[lane + 64];
            s += v1.x * v1.x + v1.y * v1.y + v1.z * v1.z + v1.w * v1.w;
            ushort4 c1;
            c1.x = f2bf(v1.x); c1.y = f2bf(v1.y); c1.z = f2bf(v1.z); c1.w = f2bf(v1.w);
            ((ushort4*)orow)[lane + 64] = c1;
        }
        s = wave_sum(s);
        if (lane == 0) invn[n] = 1.0f / sqrtf(s);
    } else if (b < 1600) {
        const int t = b - 1024;
        const int n0 = (t % 48) * 32;  // over 1536
        const int k0 = (t / 48) * 32;  // over 384
        const int tx = tid & 31, ty = tid >> 5;  // ty 0..7
        #pragma unroll
        for (int q = 0; q < 4; ++q)
            tile[ty + q * 8][tx] = W[(k0 + ty + q * 8) * HE + n0 + tx];
        __syncthreads();
        #pragma unroll
        for (int q = 0; q < 4; ++q)
            Wt[(n0 + ty + q * 8) * EMB + k0 + tx] = f2bf(tile[tx][ty + q * 8]);
    } else {
        const int t = b - 1600;
        ((float4*)attacc)[t * 256 + tid] = make_float4(0.f, 0.f, 0.f, 0.f);
    }
}

// -------------------------------------------- X = E @ W (bf16 MFMA) + fused att dots
// A: Ebf [4096,384], B: Wt [1536,384], C: Xb bf16 [4096,1536].
// 128x128 tile, BK=32, 4 waves each 64x64 (4x4 of 16x16x32).
// Epilogue: Xb write + per-row partial a_src/a_dst (each 128-col tile is within one head).
__global__ __launch_bounds__(256) void gemm_attn(const unsigned short* __restrict__ Ebf,
                                                 const unsigned short* __restrict__ Wt,
                                                 const float* __restrict__ attS,
                                                 const float* __restrict__ attD,
                                                 unsigned short* __restrict__ Xb,
                                                 float* __restrict__ asrc,
                                                 float* __restrict__ adst) {
    __shared__ unsigned short As[128 * 32];
    __shared__ unsigned short Bs[128 * 32];
    const int tid = threadIdx.x;
    const int lane = tid & 63;
    const int wave = tid >> 6;
    const int m0 = blockIdx.y * 128;
    const int n0 = blockIdx.x * 128;
    const int wr = (wave >> 1) * 64;
    const int wc = (wave & 1) * 64;
    const int quad = lane >> 4;
    const int l16 = lane & 15;

    // staging addresses: rows of 32 bf16 = 64B; one inst = 64 lanes x 16B = 16 rows
    const char* Ab = (const char*)Ebf + (size_t)(m0 + wave * 32 + (lane >> 2)) * 768 + (lane & 3) * 16;
    const char* Bb = (const char*)Wt  + (size_t)(n0 + wave * 32 + (lane >> 2)) * 768 + (lane & 3) * 16;
    char* AsB = (char*)As + wave * 32 * 64;
    char* BsB = (char*)Bs + wave * 32 * 64;

    f32x4 acc[4][4];
    #pragma unroll
    for (int i = 0; i < 4; ++i)
        #pragma unroll
        for (int j = 0; j < 4; ++j) acc[i][j] = 0.f;

    for (int kt = 0; kt < 12; ++kt) {
        const int kb = kt * 64;
        __syncthreads();
        gl2lds16(Ab + kb,            AsB);
        gl2lds16(Ab + kb + 16 * 768, AsB + 16 * 64);
        gl2lds16(Bb + kb,            BsB);
        gl2lds16(Bb + kb + 16 * 768, BsB + 16 * 64);
        __syncthreads();

        bf16x8 af[4], bfr[4];
        #pragma unroll
        for (int t = 0; t < 4; ++t) {
            af[t]  = *(const bf16x8*)(&As[(wr + t * 16 + l16) * 32 + quad * 8]);
            bfr[t] = *(const bf16x8*)(&Bs[(wc + t * 16 + l16) * 32 + quad * 8]);
        }
        #pragma unroll
        for (int ti = 0; ti < 4; ++ti)
            #pragma unroll
            for (int tj = 0; tj < 4; ++tj)
                acc[ti][tj] = __builtin_amdgcn_mfma_f32_16x16x32_bf16(
                    af[ti], bfr[tj], acc[ti][tj], 0, 0, 0);
    }

    // epilogue 1: att partials. cols n0+wc..+63 lie within head hblk (384 = 3*128).
    const int hblk = (n0 + wc) / EMB;
    float aS[4], aD[4];
    #pragma unroll
    for (int tj = 0; tj < 4; ++tj) {
        int col = n0 + wc + tj * 16 + l16;
        aS[tj] = attS[col];
        aD[tj] = attD[col];
    }
    #pragma unroll
    for (int ti = 0; ti < 4; ++ti)
        #pragma unroll
        for (int r = 0; r < 4; ++r) {
            float ps = 0.f, pd = 0.f;
            #pragma unroll
            for (int tj = 0; tj < 4; ++tj) {
                float v = acc[ti][tj][r];
                ps += v * aS[tj];
                pd += v * aD[tj];
            }
            #pragma unroll
            for (int off = 1; off < 16; off <<= 1) {
                ps += __shfl_xor(ps, off, 64);
                pd += __shfl_xor(pd, off, 64);
            }
            if (l16 == 0) {
                int row = m0 + wr + ti * 16 + quad * 4 + r;
                atomicAdd(&asrc[row * HEADS + hblk], ps);
                atomicAdd(&adst[row * HEADS + hblk], pd);
            }
        }

    // epilogue 2: Xb write (D row = quad*4+reg, col = l16)
    #pragma unroll
    for (int ti = 0; ti < 4; ++ti)
        #pragma unroll
        for (int tj = 0; tj < 4; ++tj) {
            int col = n0 + wc + tj * 16 + l16;
            #pragma unroll
            for (int r = 0; r < 4; ++r) {
                int row = m0 + wr + ti * 16 + quad * 4 + r;
                Xb[row * HE + col] = f2bf(acc[ti][tj][r]);
            }
        }
}

// ------------------------- banded mask + per-head softmax + aggregation
__global__ __launch_bounds__(256) void band_attn(const float* __restrict__ E,
                                                 const float* __restrict__ invn,
                                                 const float* __restrict__ asrc,
                                                 const float* __restrict__ adst,
                                                 const unsigned short* __restrict__ Xb,
                                                 const float* __restrict__ bias,
                                                 float* __restrict__ out) {
    const int i = blockIdx.x;
    const int tid = threadIdx.x;
    const int lane = tid & 63, wave = tid >> 6;

    __shared__ float ei[EMB];
    __shared__ float alpha_s[HEADS][BW];
    __shared__ int maskv[BW];
    __shared__ int list[BW];
    __shared__ int cnt;

    for (int d = tid; d < EMB; d += 256) ei[d] = E[i * EMB + d];
    __syncthreads();

    const float inv_i = invn[i];
    // fp32 banded cos-sim + decay threshold (must stay fp32: threshold flips matter)
    for (int it = 0; it < 6; ++it) {
        int jo = it * 4 + wave;  // wave-uniform
        if (jo < BW) {
            int j = i - BAND + jo;
            bool valid = (j >= 0) && (j < N_SPANS);
            float s = 0.f;
            if (valid) {
                const float* ej = E + j * EMB;
                #pragma unroll
                for (int m = 0; m < 6; ++m) {
                    int d = m * 64 + lane;
                    s += ei[d] * ej[d];
                }
                s = wave_sum(s);
            }
            if (lane == 0) {
                int mflag = 0;
                if (valid) {
                    float cosv = s * inv_i * invn[j];
                    int dd = jo - BAND; if (dd < 0) dd = -dd;
                    float a = cosv * expf(-(float)dd * 0.2f);
                    if (a > 0.1f) mflag = 1;
                }
                maskv[jo] = mflag;
            }
        }
    }
    __syncthreads();

    // per-head masked softmax over the 23-wide band: wave w = head w
    {
        const int h = wave;
        const int jo = lane;
        float logit = -INFINITY;
        if (jo < BW && maskv[jo]) {
            int j = i - BAND + jo;
            float z = adst[i * HEADS + h] + asrc[j * HEADS + h];
            logit = (z >= 0.f) ? z : 0.2f * z;  // leaky_relu 0.2
        }
        float mx = wave_max(logit);  // diag always present -> finite
        float ex = (jo < BW) ? expf(logit - mx) : 0.f;
        float sm = wave_sum(ex);
        if (jo < BW) alpha_s[h][jo] = ex / sm;
    }
    __syncthreads();

    if (tid == 0) {
        int c = 0;
        for (int jo = 0; jo < BW; ++jo) if (maskv[jo]) list[c++] = jo;
        cnt = c;
    }
    __syncthreads();

    const int c = cnt;
    for (int e = tid; e < EMB; e += 256) {
        float acc = 0.f;
        for (int ii = 0; ii < c; ++ii) {
            int jo = list[ii];
            int j = i - BAND + jo;
            const unsigned short* xb = Xb + j * HE + e;
            #pragma unroll
            for (int h = 0; h < HEADS; ++h)
                acc += alpha_s[h][jo] * bf2f(xb[h * EMB]);
        }
        out[i * EMB + e] = 0.25f * acc + bias[e];  // mean over 4 heads + bias
    }
}

extern "C" void kernel_launch(void* const* d_in, const int* in_sizes, int n_in,
                              void* d_out, int out_size, void* d_ws, size_t ws_size,
                              hipStream_t stream) {
    const float* E       = (const float*)d_in[0];
    // d_in[1] span_positions: unused by the reference computation
    const float* W       = (const float*)d_in[2];
    const float* att_src = (const float*)d_in[3];
    const float* att_dst = (const float*)d_in[4];
    const float* bias    = (const float*)d_in[5];
    float* out = (float*)d_out;

    char* ws = (char*)d_ws;
    unsigned short* Xb  = (unsigned short*)ws;                 // 4096*1536*2 = 12582912
    unsigned short* Ebf = (unsigned short*)(ws + 12582912);    // 4096*384*2  = 3145728
    unsigned short* Wt  = (unsigned short*)(ws + 15728640);    // 1536*384*2  = 1179648
    float* invn         = (float*)(ws + 16908288);             // 4096*4      = 16384
    float* asrc         = (float*)(ws + 16924672);             // 16384*4     = 65536
    float* adst         = (float*)(ws + 16990208);             // 16384*4     = 65536

    prep<<<1632, 256, 0, stream>>>(E, W, Ebf, Wt, invn, asrc /* zeroes asrc+adst */);
    gemm_attn<<<dim3(12, 32), 256, 0, stream>>>(Ebf, Wt, att_src, att_dst, Xb, asrc, adst);
    band_attn<<<4096, 256, 0, stream>>>(E, invn, asrc, adst, Xb, bias, out);
}

// Round 3
// 118.836 us; speedup vs baseline: 1.0149x; 1.0027x over previous
//
#include <hip/hip_runtime.h>
#include <hip/hip_bf16.h>
#include <math.h>

#define N_SPANS 4096
#define EMB 384
#define HEADS 4
#define HE (HEADS * EMB)   // 1536
#define BAND 11            // exp(-12/5)=0.0907 < 0.1 => |i-j|>=12 never passes threshold
#define BW (2 * BAND + 1)  // 23

typedef short bf16x8 __attribute__((ext_vector_type(8)));
typedef float f32x4 __attribute__((ext_vector_type(4)));

__device__ __forceinline__ unsigned short f2bf(float f) {
    union { float f; unsigned u; } x; x.f = f;
    unsigned r = x.u + 0x7fffu + ((x.u >> 16) & 1u);  // RNE
    return (unsigned short)(r >> 16);
}
__device__ __forceinline__ float bf2f(unsigned short u) {
    union { unsigned u; float f; } x; x.u = ((unsigned)u) << 16; return x.f;
}

__device__ __forceinline__ float wave_sum(float v) {
    #pragma unroll
    for (int off = 32; off; off >>= 1) v += __shfl_xor(v, off, 64);
    return v;
}
__device__ __forceinline__ float wave_max(float v) {
    #pragma unroll
    for (int off = 32; off; off >>= 1) v = fmaxf(v, __shfl_xor(v, off, 64));
    return v;
}

// async global->LDS, 16B per lane, dest = wave-uniform base + lane*16
__device__ __forceinline__ void gl2lds16(const void* g, void* l) {
    __builtin_amdgcn_global_load_lds(
        (const __attribute__((address_space(1))) void*)(uintptr_t)g,
        (__attribute__((address_space(3))) void*)(unsigned)(uintptr_t)l,
        16, 0, 0);
}

// ------------------------------------------------------------------ prep
// blocks [0,1024): row inv-norms + E fp32->bf16 cast (wave per row)
// blocks [1024,1600): W [384,1536] -> Wt bf16 [1536,384]
// blocks [1600,1632): zero asrc/adst (32768 floats)
__global__ __launch_bounds__(256) void prep(const float* __restrict__ E,
                                            const float* __restrict__ W,
                                            unsigned short* __restrict__ Ebf,
                                            unsigned short* __restrict__ Wt,
                                            float* __restrict__ invn,
                                            float* __restrict__ attacc) {
    __shared__ float tile[32][33];
    const int b = blockIdx.x;
    const int tid = threadIdx.x;
    if (b < 1024) {
        const int lane = tid & 63, w = tid >> 6;
        const int n = b * 4 + w;
        const float4* er = (const float4*)(E + n * EMB);  // 96 chunks
        unsigned short* orow = Ebf + n * EMB;
        float s = 0.f;
        float4 v0 = er[lane];
        s += v0.x * v0.x + v0.y * v0.y + v0.z * v0.z + v0.w * v0.w;
        ushort4 c0;
        c0.x = f2bf(v0.x); c0.y = f2bf(v0.y); c0.z = f2bf(v0.z); c0.w = f2bf(v0.w);
        ((ushort4*)orow)[lane] = c0;
        if (lane < 32) {
            float4 v1 = er[lane + 64];
            s += v1.x * v1.x + v1.y * v1.y + v1.z * v1.z + v1.w * v1.w;
            ushort4 c1;
            c1.x = f2bf(v1.x); c1.y = f2bf(v1.y); c1.z = f2bf(v1.z); c1.w = f2bf(v1.w);
            ((ushort4*)orow)[lane + 64] = c1;
        }
        s = wave_sum(s);
        if (lane == 0) invn[n] = 1.0f / sqrtf(s);
    } else if (b < 1600) {
        const int t = b - 1024;
        const int n0 = (t % 48) * 32;  // over 1536
        const int k0 = (t / 48) * 32;  // over 384
        const int tx = tid & 31, ty = tid >> 5;  // ty 0..7
        #pragma unroll
        for (int q = 0; q < 4; ++q)
            tile[ty + q * 8][tx] = W[(k0 + ty + q * 8) * HE + n0 + tx];
        __syncthreads();
        #pragma unroll
        for (int q = 0; q < 4; ++q)
            Wt[(n0 + ty + q * 8) * EMB + k0 + tx] = f2bf(tile[tx][ty + q * 8]);
    } else {
        const int t = b - 1600;
        ((float4*)attacc)[t * 256 + tid] = make_float4(0.f, 0.f, 0.f, 0.f);
    }
}

// -------------------------------------------- X = E @ W (bf16 MFMA) + fused att dots
// A: Ebf [4096,384], B: Wt [1536,384], C: Xb bf16 [4096,1536].
// 128x128 tile, BK=32, 4 waves each 64x64 (4x4 of 16x16x32).
// Epilogue: Xb write + per-row partial a_src/a_dst (each 128-col tile is within one head).
__global__ __launch_bounds__(256) void gemm_attn(const unsigned short* __restrict__ Ebf,
                                                 const unsigned short* __restrict__ Wt,
                                                 const float* __restrict__ attS,
                                                 const float* __restrict__ attD,
                                                 unsigned short* __restrict__ Xb,
                                                 float* __restrict__ asrc,
                                                 float* __restrict__ adst) {
    __shared__ unsigned short As[128 * 32];
    __shared__ unsigned short Bs[128 * 32];
    const int tid = threadIdx.x;
    const int lane = tid & 63;
    const int wave = tid >> 6;
    const int m0 = blockIdx.y * 128;
    const int n0 = blockIdx.x * 128;
    const int wr = (wave >> 1) * 64;
    const int wc = (wave & 1) * 64;
    const int quad = lane >> 4;
    const int l16 = lane & 15;

    // staging addresses: rows of 32 bf16 = 64B; one inst = 64 lanes x 16B = 16 rows
    const char* Ab = (const char*)Ebf + (size_t)(m0 + wave * 32 + (lane >> 2)) * 768 + (lane & 3) * 16;
    const char* Bb = (const char*)Wt  + (size_t)(n0 + wave * 32 + (lane >> 2)) * 768 + (lane & 3) * 16;
    char* AsB = (char*)As + wave * 32 * 64;
    char* BsB = (char*)Bs + wave * 32 * 64;

    f32x4 acc[4][4];
    #pragma unroll
    for (int i = 0; i < 4; ++i)
        #pragma unroll
        for (int j = 0; j < 4; ++j) acc[i][j] = 0.f;

    for (int kt = 0; kt < 12; ++kt) {
        const int kb = kt * 64;
        __syncthreads();
        gl2lds16(Ab + kb,            AsB);
        gl2lds16(Ab + kb + 16 * 768, AsB + 16 * 64);
        gl2lds16(Bb + kb,            BsB);
        gl2lds16(Bb + kb + 16 * 768, BsB + 16 * 64);
        __syncthreads();

        bf16x8 af[4], bfr[4];
        #pragma unroll
        for (int t = 0; t < 4; ++t) {
            af[t]  = *(const bf16x8*)(&As[(wr + t * 16 + l16) * 32 + quad * 8]);
            bfr[t] = *(const bf16x8*)(&Bs[(wc + t * 16 + l16) * 32 + quad * 8]);
        }
        #pragma unroll
        for (int ti = 0; ti < 4; ++ti)
            #pragma unroll
            for (int tj = 0; tj < 4; ++tj)
                acc[ti][tj] = __builtin_amdgcn_mfma_f32_16x16x32_bf16(
                    af[ti], bfr[tj], acc[ti][tj], 0, 0, 0);
    }

    // epilogue 1: att partials. cols n0+wc..+63 lie within head hblk (384 = 3*128).
    const int hblk = (n0 + wc) / EMB;
    float aS[4], aD[4];
    #pragma unroll
    for (int tj = 0; tj < 4; ++tj) {
        int col = n0 + wc + tj * 16 + l16;
        aS[tj] = attS[col];
        aD[tj] = attD[col];
    }
    #pragma unroll
    for (int ti = 0; ti < 4; ++ti)
        #pragma unroll
        for (int r = 0; r < 4; ++r) {
            float ps = 0.f, pd = 0.f;
            #pragma unroll
            for (int tj = 0; tj < 4; ++tj) {
                float v = acc[ti][tj][r];
                ps += v * aS[tj];
                pd += v * aD[tj];
            }
            #pragma unroll
            for (int off = 1; off < 16; off <<= 1) {
                ps += __shfl_xor(ps, off, 64);
                pd += __shfl_xor(pd, off, 64);
            }
            if (l16 == 0) {
                int row = m0 + wr + ti * 16 + quad * 4 + r;
                atomicAdd(&asrc[row * HEADS + hblk], ps);
                atomicAdd(&adst[row * HEADS + hblk], pd);
            }
        }

    // epilogue 2: Xb write (D row = quad*4+reg, col = l16)
    #pragma unroll
    for (int ti = 0; ti < 4; ++ti)
        #pragma unroll
        for (int tj = 0; tj < 4; ++tj) {
            int col = n0 + wc + tj * 16 + l16;
            #pragma unroll
            for (int r = 0; r < 4; ++r) {
                int row = m0 + wr + ti * 16 + quad * 4 + r;
                Xb[row * HE + col] = f2bf(acc[ti][tj][r]);
            }
        }
}

// ------------------------- banded mask + per-head softmax + aggregation
__global__ __launch_bounds__(256) void band_attn(const float* __restrict__ E,
                                                 const float* __restrict__ invn,
                                                 const float* __restrict__ asrc,
                                                 const float* __restrict__ adst,
                                                 const unsigned short* __restrict__ Xb,
                                                 const float* __restrict__ bias,
                                                 float* __restrict__ out) {
    const int i = blockIdx.x;
    const int tid = threadIdx.x;
    const int lane = tid & 63, wave = tid >> 6;

    __shared__ float ei[EMB];
    __shared__ float alpha_s[HEADS][BW];
    __shared__ int maskv[BW];
    __shared__ int list[BW];
    __shared__ int cnt;

    for (int d = tid; d < EMB; d += 256) ei[d] = E[i * EMB + d];
    __syncthreads();

    const float inv_i = invn[i];
    // fp32 banded cos-sim + decay threshold (must stay fp32: threshold flips matter)
    for (int it = 0; it < 6; ++it) {
        int jo = it * 4 + wave;  // wave-uniform
        if (jo < BW) {
            int j = i - BAND + jo;
            bool valid = (j >= 0) && (j < N_SPANS);
            float s = 0.f;
            if (valid) {
                const float* ej = E + j * EMB;
                #pragma unroll
                for (int m = 0; m < 6; ++m) {
                    int d = m * 64 + lane;
                    s += ei[d] * ej[d];
                }
                s = wave_sum(s);
            }
            if (lane == 0) {
                int mflag = 0;
                if (valid) {
                    float cosv = s * inv_i * invn[j];
                    int dd = jo - BAND; if (dd < 0) dd = -dd;
                    float a = cosv * expf(-(float)dd * 0.2f);
                    if (a > 0.1f) mflag = 1;
                }
                maskv[jo] = mflag;
            }
        }
    }
    __syncthreads();

    // per-head masked softmax over the 23-wide band: wave w = head w
    {
        const int h = wave;
        const int jo = lane;
        float logit = -INFINITY;
        if (jo < BW && maskv[jo]) {
            int j = i - BAND + jo;
            float z = adst[i * HEADS + h] + asrc[j * HEADS + h];
            logit = (z >= 0.f) ? z : 0.2f * z;  // leaky_relu 0.2
        }
        float mx = wave_max(logit);  // diag always present -> finite
        float ex = (jo < BW) ? expf(logit - mx) : 0.f;
        float sm = wave_sum(ex);
        if (jo < BW) alpha_s[h][jo] = ex / sm;
    }
    __syncthreads();

    if (tid == 0) {
        int c = 0;
        for (int jo = 0; jo < BW; ++jo) if (maskv[jo]) list[c++] = jo;
        cnt = c;
    }
    __syncthreads();

    const int c = cnt;
    for (int e = tid; e < EMB; e += 256) {
        float acc = 0.f;
        for (int ii = 0; ii < c; ++ii) {
            int jo = list[ii];
            int j = i - BAND + jo;
            const unsigned short* xb = Xb + j * HE + e;
            #pragma unroll
            for (int h = 0; h < HEADS; ++h)
                acc += alpha_s[h][jo] * bf2f(xb[h * EMB]);
        }
        out[i * EMB + e] = 0.25f * acc + bias[e];  // mean over 4 heads + bias
    }
}

extern "C" void kernel_launch(void* const* d_in, const int* in_sizes, int n_in,
                              void* d_out, int out_size, void* d_ws, size_t ws_size,
                              hipStream_t stream) {
    const float* E       = (const float*)d_in[0];
    // d_in[1] span_positions: unused by the reference computation
    const float* W       = (const float*)d_in[2];
    const float* att_src = (const float*)d_in[3];
    const float* att_dst = (const float*)d_in[4];
    const float* bias    = (const float*)d_in[5];
    float* out = (float*)d_out;

    char* ws = (char*)d_ws;
    unsigned short* Xb  = (unsigned short*)ws;                 // 4096*1536*2 = 12582912
    unsigned short* Ebf = (unsigned short*)(ws + 12582912);    // 4096*384*2  = 3145728
    unsigned short* Wt  = (unsigned short*)(ws + 15728640);    // 1536*384*2  = 1179648
    float* invn         = (float*)(ws + 16908288);             // 4096*4      = 16384
    float* asrc         = (float*)(ws + 16924672);             // 16384*4     = 65536
    float* adst         = (float*)(ws + 16990208);             // 16384*4     = 65536

    prep<<<1632, 256, 0, stream>>>(E, W, Ebf, Wt, invn, asrc /* zeroes asrc+adst */);
    gemm_attn<<<dim3(12, 32), 256, 0, stream>>>(Ebf, Wt, att_src, att_dst, Xb, asrc, adst);
    band_attn<<<4096, 256, 0, stream>>>(E, invn, asrc, adst, Xb, bias, out);
}

// Round 4
// 109.565 us; speedup vs baseline: 1.1008x; 1.0846x over previous
//
#include <hip/hip_runtime.h>
#include <hip/hip_bf16.h>
#include <math.h>

#define N_SPANS 4096
#define EMB 384
#define HEADS 4
#define HE (HEADS * EMB)   // 1536
#define BAND 11            // exp(-12/5)=0.0907 < 0.1 => |i-j|>=12 never passes threshold
#define BW (2 * BAND + 1)  // 23

typedef short bf16x8 __attribute__((ext_vector_type(8)));
typedef float f32x4 __attribute__((ext_vector_type(4)));

__device__ __forceinline__ unsigned short f2bf(float f) {
    union { float f; unsigned u; } x; x.f = f;
    unsigned r = x.u + 0x7fffu + ((x.u >> 16) & 1u);  // RNE
    return (unsigned short)(r >> 16);
}
__device__ __forceinline__ float bf2f(unsigned short u) {
    union { unsigned u; float f; } x; x.u = ((unsigned)u) << 16; return x.f;
}

__device__ __forceinline__ float wave_sum(float v) {
    #pragma unroll
    for (int off = 32; off; off >>= 1) v += __shfl_xor(v, off, 64);
    return v;
}
__device__ __forceinline__ float wave_max(float v) {
    #pragma unroll
    for (int off = 32; off; off >>= 1) v = fmaxf(v, __shfl_xor(v, off, 64));
    return v;
}

// async global->LDS, 16B per lane, dest = wave-uniform base + lane*16
__device__ __forceinline__ void gl2lds16(const void* g, void* l) {
    __builtin_amdgcn_global_load_lds(
        (const __attribute__((address_space(1))) void*)(uintptr_t)g,
        (__attribute__((address_space(3))) void*)(unsigned)(uintptr_t)l,
        16, 0, 0);
}

// ------------------------------------------------------------------ prep
// blocks [0,1024): wave per node n: inv-norm + Ebf cast + forward band dots d=1..11
// blocks [1024,1600): W [384,1536] -> Wt bf16 [1536,384]
// blocks [1600,1632): zero asrc/adst (32768 floats)
__global__ __launch_bounds__(256) void prep(const float* __restrict__ E,
                                            const float* __restrict__ W,
                                            unsigned short* __restrict__ Ebf,
                                            unsigned short* __restrict__ Wt,
                                            float* __restrict__ invn,
                                            float* __restrict__ Dots,
                                            float* __restrict__ attacc) {
    __shared__ float tile[32][33];
    const int b = blockIdx.x;
    const int tid = threadIdx.x;
    if (b < 1024) {
        const int lane = tid & 63, w = tid >> 6;
        const int n = b * 4 + w;
        const float* er = E + (size_t)n * EMB;
        const int dmax = (n >= N_SPANS - BAND) ? (N_SPANS - 1 - n) : BAND;  // wave-uniform
        // clamped neighbor row bases (always in-bounds addresses)
        const float* nb[BAND];
        #pragma unroll
        for (int d = 1; d <= BAND; ++d) {
            int j = n + d; if (j > N_SPANS - 1) j = N_SPANS - 1;
            nb[d - 1] = E + (size_t)j * EMB;
        }
        float acc[12];
        #pragma unroll
        for (int d = 0; d < 12; ++d) acc[d] = 0.f;
        float ev[6];
        #pragma unroll
        for (int m = 0; m < 6; ++m) {
            const int k = m * 64 + lane;
            const float v = er[k];
            ev[m] = v;
            acc[0] += v * v;
            #pragma unroll
            for (int d = 1; d <= BAND; ++d) {
                float u = nb[d - 1][k];
                acc[d] += (d <= dmax) ? v * u : 0.f;
            }
        }
        #pragma unroll
        for (int m = 0; m < 6; ++m)
            Ebf[(size_t)n * EMB + m * 64 + lane] = f2bf(ev[m]);
        #pragma unroll
        for (int d = 0; d < 12; ++d) acc[d] = wave_sum(acc[d]);
        float dval = 0.f;
        #pragma unroll
        for (int d = 1; d <= BAND; ++d) if (lane == d) dval = acc[d];
        if (lane >= 1 && lane <= BAND) Dots[(size_t)n * 12 + lane] = dval;
        if (lane == 0) invn[n] = 1.0f / sqrtf(acc[0]);
    } else if (b < 1600) {
        const int t = b - 1024;
        const int n0 = (t % 48) * 32;  // over 1536
        const int k0 = (t / 48) * 32;  // over 384
        const int tx = tid & 31, ty = tid >> 5;  // ty 0..7
        #pragma unroll
        for (int q = 0; q < 4; ++q)
            tile[ty + q * 8][tx] = W[(k0 + ty + q * 8) * HE + n0 + tx];
        __syncthreads();
        #pragma unroll
        for (int q = 0; q < 4; ++q)
            Wt[(n0 + ty + q * 8) * EMB + k0 + tx] = f2bf(tile[tx][ty + q * 8]);
    } else {
        const int t = b - 1600;
        ((float4*)attacc)[t * 256 + tid] = make_float4(0.f, 0.f, 0.f, 0.f);
    }
}

// -------------------------------------------- X = E @ W (bf16 MFMA) + fused att dots
__global__ __launch_bounds__(256) void gemm_attn(const unsigned short* __restrict__ Ebf,
                                                 const unsigned short* __restrict__ Wt,
                                                 const float* __restrict__ attS,
                                                 const float* __restrict__ attD,
                                                 unsigned short* __restrict__ Xb,
                                                 float* __restrict__ asrc,
                                                 float* __restrict__ adst) {
    __shared__ unsigned short As[128 * 32];
    __shared__ unsigned short Bs[128 * 32];
    const int tid = threadIdx.x;
    const int lane = tid & 63;
    const int wave = tid >> 6;
    const int m0 = blockIdx.y * 128;
    const int n0 = blockIdx.x * 128;
    const int wr = (wave >> 1) * 64;
    const int wc = (wave & 1) * 64;
    const int quad = lane >> 4;
    const int l16 = lane & 15;

    const char* Ab = (const char*)Ebf + (size_t)(m0 + wave * 32 + (lane >> 2)) * 768 + (lane & 3) * 16;
    const char* Bb = (const char*)Wt  + (size_t)(n0 + wave * 32 + (lane >> 2)) * 768 + (lane & 3) * 16;
    char* AsB = (char*)As + wave * 32 * 64;
    char* BsB = (char*)Bs + wave * 32 * 64;

    f32x4 acc[4][4];
    #pragma unroll
    for (int i = 0; i < 4; ++i)
        #pragma unroll
        for (int j = 0; j < 4; ++j) acc[i][j] = 0.f;

    for (int kt = 0; kt < 12; ++kt) {
        const int kb = kt * 64;
        __syncthreads();
        gl2lds16(Ab + kb,            AsB);
        gl2lds16(Ab + kb + 16 * 768, AsB + 16 * 64);
        gl2lds16(Bb + kb,            BsB);
        gl2lds16(Bb + kb + 16 * 768, BsB + 16 * 64);
        __syncthreads();

        bf16x8 af[4], bfr[4];
        #pragma unroll
        for (int t = 0; t < 4; ++t) {
            af[t]  = *(const bf16x8*)(&As[(wr + t * 16 + l16) * 32 + quad * 8]);
            bfr[t] = *(const bf16x8*)(&Bs[(wc + t * 16 + l16) * 32 + quad * 8]);
        }
        #pragma unroll
        for (int ti = 0; ti < 4; ++ti)
            #pragma unroll
            for (int tj = 0; tj < 4; ++tj)
                acc[ti][tj] = __builtin_amdgcn_mfma_f32_16x16x32_bf16(
                    af[ti], bfr[tj], acc[ti][tj], 0, 0, 0);
    }

    // epilogue 1: att partials (cols n0+wc..+63 lie within one head; 384 = 3*128)
    const int hblk = (n0 + wc) / EMB;
    float aS[4], aD[4];
    #pragma unroll
    for (int tj = 0; tj < 4; ++tj) {
        int col = n0 + wc + tj * 16 + l16;
        aS[tj] = attS[col];
        aD[tj] = attD[col];
    }
    #pragma unroll
    for (int ti = 0; ti < 4; ++ti)
        #pragma unroll
        for (int r = 0; r < 4; ++r) {
            float ps = 0.f, pd = 0.f;
            #pragma unroll
            for (int tj = 0; tj < 4; ++tj) {
                float v = acc[ti][tj][r];
                ps += v * aS[tj];
                pd += v * aD[tj];
            }
            #pragma unroll
            for (int off = 1; off < 16; off <<= 1) {
                ps += __shfl_xor(ps, off, 64);
                pd += __shfl_xor(pd, off, 64);
            }
            if (l16 == 0) {
                int row = m0 + wr + ti * 16 + quad * 4 + r;
                atomicAdd(&asrc[row * HEADS + hblk], ps);
                atomicAdd(&adst[row * HEADS + hblk], pd);
            }
        }

    // epilogue 2: Xb write (D row = quad*4+reg, col = l16)
    #pragma unroll
    for (int ti = 0; ti < 4; ++ti)
        #pragma unroll
        for (int tj = 0; tj < 4; ++tj) {
            int col = n0 + wc + tj * 16 + l16;
            #pragma unroll
            for (int r = 0; r < 4; ++r) {
                int row = m0 + wr + ti * 16 + quad * 4 + r;
                Xb[row * HE + col] = f2bf(acc[ti][tj][r]);
            }
        }
}

// ------------------- wave-per-node: flags from precomputed dots, softmax, aggregate
__global__ __launch_bounds__(256) void band_attn(const float* __restrict__ invn,
                                                 const float* __restrict__ Dots,
                                                 const float* __restrict__ asrc,
                                                 const float* __restrict__ adst,
                                                 const unsigned short* __restrict__ Xb,
                                                 const float* __restrict__ bias,
                                                 float* __restrict__ out) {
    __shared__ float sAl[4][BW][4];   // [wave][jo][h], 16B-aligned rows
    __shared__ int sList[4][24];
    const int tid = threadIdx.x, lane = tid & 63, w = tid >> 6;
    const int i = blockIdx.x * 4 + w;
    const int jo = lane;
    const int j = i - BAND + jo;
    const bool inb = (jo < BW) && (j >= 0) && (j < N_SPANS);
    const int jc = inb ? j : i;

    // fetch precomputed symmetric dot
    float dotv = 0.f;
    if (inb) {
        if (jo < BAND)      dotv = Dots[(size_t)j * 12 + (BAND - jo)];  // dot(j, j+(11-jo)) = dot(j,i)
        else if (jo > BAND) dotv = Dots[(size_t)i * 12 + (jo - BAND)];
    }
    bool flag;
    if (jo == BAND) {
        flag = true;  // diagonal: cos=1 > 0.1 always
    } else {
        int dd = jo < BAND ? BAND - jo : jo - BAND;
        float a = ((dotv * invn[i]) * invn[jc]) * expf(-(float)dd * 0.2f);
        flag = inb && (a > 0.1f);
    }

    unsigned long long mbits = __ballot(flag);
    const int cnt = __popcll(mbits);
    const int rank = __popcll(mbits & ((1ull << jo) - 1ull));
    if (flag) sList[w][rank] = jo;

    // per-head masked softmax across the wave's 23 band lanes
    const float4 ad = ((const float4*)adst)[i];          // wave-uniform
    const float4 as = inb ? ((const float4*)asrc)[jc] : make_float4(0.f, 0.f, 0.f, 0.f);
    float al[4];
    #pragma unroll
    for (int h = 0; h < 4; ++h) {
        float z = (&ad.x)[h] + (&as.x)[h];
        z = (z >= 0.f) ? z : 0.2f * z;                   // leaky_relu 0.2
        float lg = flag ? z : -INFINITY;
        float mx = wave_max(lg);                         // diagonal present -> finite
        float ex = flag ? expf(lg - mx) : 0.f;
        float sm = wave_sum(ex);
        al[h] = ex / sm;
    }
    if (flag) *(float4*)&sAl[w][jo][0] = make_float4(al[0], al[1], al[2], al[3]);
    // same-wave LDS producer/consumer: no barrier needed (compiler inserts lgkmcnt)

    #pragma unroll
    for (int m = 0; m < 6; ++m) {
        const int e = m * 64 + lane;
        float acc = 0.f;
        for (int ii = 0; ii < cnt; ++ii) {
            const int joL = sList[w][ii];
            const int jj = i - BAND + joL;
            const float4 a4 = *(const float4*)&sAl[w][joL][0];
            const unsigned short* xr = Xb + (size_t)jj * HE + e;
            acc += a4.x * bf2f(xr[0])   + a4.y * bf2f(xr[384])
                 + a4.z * bf2f(xr[768]) + a4.w * bf2f(xr[1152]);
        }
        out[i * EMB + e] = 0.25f * acc + bias[e];        // mean over 4 heads + bias
    }
}

extern "C" void kernel_launch(void* const* d_in, const int* in_sizes, int n_in,
                              void* d_out, int out_size, void* d_ws, size_t ws_size,
                              hipStream_t stream) {
    const float* E       = (const float*)d_in[0];
    // d_in[1] span_positions: unused by the reference computation
    const float* W       = (const float*)d_in[2];
    const float* att_src = (const float*)d_in[3];
    const float* att_dst = (const float*)d_in[4];
    const float* bias    = (const float*)d_in[5];
    float* out = (float*)d_out;

    char* ws = (char*)d_ws;
    unsigned short* Xb  = (unsigned short*)ws;                 // 0        .. 12582912
    unsigned short* Ebf = (unsigned short*)(ws + 12582912);    // 3145728
    unsigned short* Wt  = (unsigned short*)(ws + 15728640);    // 1179648
    float* invn         = (float*)(ws + 16908288);             // 16384
    float* asrc         = (float*)(ws + 16924672);             // 65536
    float* adst         = (float*)(ws + 16990208);             // 65536
    float* Dots         = (float*)(ws + 17055744);             // 4096*12*4 = 196608

    prep<<<1632, 256, 0, stream>>>(E, W, Ebf, Wt, invn, Dots, asrc /* zeroes asrc+adst */);
    gemm_attn<<<dim3(12, 32), 256, 0, stream>>>(Ebf, Wt, att_src, att_dst, Xb, asrc, adst);
    band_attn<<<1024, 256, 0, stream>>>(invn, Dots, asrc, adst, Xb, bias, out);
}